// Round 10
// baseline (60.636 us; speedup 1.0000x reference)
//
#include <hip/hip_runtime.h>

#define B_SZ   256
#define IN_F   256
#define OUT_F  256
#define NINT   15
#define IQ     64             // input features per block (IN-dim split in 4)

__device__ __forceinline__ float kan_eval(float wv, float xv,
                                          const float4* __restrict__ crow, int cbase) {
    const float kD = 2.0f / 15.0f;                 // fl32(2/15), XLA's delta bits
    float wx = wv * xv;                            // ref's exact f32 product
    float xc = fminf(fmaxf(wx, -1.0f), 1.0f);
    float u  = __builtin_fmaf(xc, 7.5f, 7.4999f);  // down-biased floor guess
    int   i0 = (int)u;                             // ∈ [0,14]
    float f0 = (float)i0;
    float blo = __fadd_rn(__fmul_rn(f0, kD), -1.0f);                   // bp[i0]
    float bhi = __fadd_rn(__fmul_rn(__fadd_rn(f0, 1.0f), kD), -1.0f);  // bp[i0+1]
    bool  up = (xc >= bhi);                        // exact searchsorted(right)-1
    int   j  = i0 + (up ? 1 : 0);                  // j<=14 automatic: bp[15] > 1 >= xc
    float bj = up ? bhi : blo;
    float dx = xc - bj;                            // ref's exact f32 sub
    float4 c = crow[cbase + j];                    // GLOBAL gather: ~4 lines/wave, L1-hot
    return __builtin_fmaf(__builtin_fmaf(__builtin_fmaf(c.w, dx, c.z), dx, c.y), dx, c.x);
}

__global__ __launch_bounds__(256, 8)
void kan_kernel(const float* __restrict__ x,
                const float* __restrict__ w,
                const float* __restrict__ bias,
                const float* __restrict__ coeffs,
                float* __restrict__ out)
{
    // bid = q*512 + bh*256 + o: the 8 blocks of one o are all ≡ o (mod 8) ->
    // same XCD -> o's 15KB coeff window + the atomic lines stay in ONE L2.
    const int o  = blockIdx.x & (OUT_F - 1);
    const int bh = (blockIdx.x >> 8) & 1;        // which batch half
    const int q  = blockIdx.x >> 9;              // which IN-quarter (0..3)
    const int b  = bh * 256 + threadIdx.x;       // batch row

    const float4* crow = reinterpret_cast<const float4*>(coeffs)
                         + ((size_t)o * IN_F + q * IQ) * NINT;
    const float4* wrow = reinterpret_cast<const float4*>(w + (size_t)o * IN_F + q * IQ);
    const float4* xrow = reinterpret_cast<const float4*>(x + (size_t)b * IN_F + q * IQ);

    float a0 = 0.f, a1 = 0.f, a2 = 0.f, a3 = 0.f;

    #pragma unroll 4
    for (int i4 = 0; i4 < IQ / 4; ++i4) {
        float4 xv = xrow[i4];
        float4 wv = wrow[i4];          // wave-uniform address -> scalar s_load path
        int cb = i4 * 4 * NINT;
        a0 += kan_eval(wv.x, xv.x, crow, cb);
        a1 += kan_eval(wv.y, xv.y, crow, cb + NINT);
        a2 += kan_eval(wv.z, xv.z, crow, cb + 2 * NINT);
        a3 += kan_eval(wv.w, xv.w, crow, cb + 3 * NINT);
    }

    float acc = (a0 + a1) + (a2 + a3);
    if (q == 0) acc += bias[o];        // exactly once per (b,o): one q==0 block per b-half
    // out zeroed by memsetAsync each launch; 4 commutative adds per element.
    atomicAdd(out + (size_t)b * OUT_F + o, acc);
}

extern "C" void kernel_launch(void* const* d_in, const int* in_sizes, int n_in,
                              void* d_out, int out_size, void* d_ws, size_t ws_size,
                              hipStream_t stream) {
    (void)d_ws; (void)ws_size;

    const float *x = nullptr, *wgt = nullptr, *bias = nullptr, *coeffs = nullptr;
    for (int i = 0; i < n_in; ++i) {
        switch (in_sizes[i]) {
            case 512 * 256:           x      = (const float*)d_in[i]; break;
            case 256 * 256:           wgt    = (const float*)d_in[i]; break;
            case 256:                 bias   = (const float*)d_in[i]; break;
            case 256 * 256 * 15 * 4:  coeffs = (const float*)d_in[i]; break;
            default: break;
        }
    }

    hipMemsetAsync(d_out, 0, (size_t)out_size * sizeof(float), stream);
    kan_kernel<<<8 * OUT_F, B_SZ, 0, stream>>>(x, wgt, bias, coeffs, (float*)d_out);
}

// Round 12
// 41.976 us; speedup vs baseline: 1.4445x; 1.4445x over previous
//
#include <hip/hip_runtime.h>

#define B_SZ   512
#define IN_F   256
#define OUT_F  256
#define NINT   15
#define IHALF  128            // input features per block (IN-dim split in 2)
#define NC4    (IHALF * NINT) // float4 coeff entries per block = 1920

typedef const __attribute__((address_space(1))) void gvoid_t;
typedef __attribute__((address_space(3))) void lvoid_t;

// prep: transpose x -> xq[i4][b] (coalesced main-kernel reads) and zero out[].
// Both ranges are exactly 32768 float4s -> grid 128 x 256.
__global__ __launch_bounds__(256) void prep_kernel(const float* __restrict__ x,
                                                   float4* __restrict__ xq,
                                                   float4* __restrict__ out4) {
    int T = blockIdx.x * 256 + threadIdx.x;   // 0..32767
    int b = T >> 6, i4 = T & 63;
    float4 v = reinterpret_cast<const float4*>(x)[T];  // coalesced read
    xq[i4 * 512 + b] = v;                              // one-time scatter write
    out4[T] = make_float4(0.f, 0.f, 0.f, 0.f);
}

// validated general path (R5/R6): exact XLA-f32-linspace binning + LDS gather
__device__ __forceinline__ float kan_slow(float wv, float xv,
                                          const float4* __restrict__ sc, int cbase) {
    const float kD = 2.0f / 15.0f;
    float wx = wv * xv;
    float xc = fminf(fmaxf(wx, -1.0f), 1.0f);
    float u  = __builtin_fmaf(xc, 7.5f, 7.4999f);
    int   i0 = (int)u;
    float f0 = (float)i0;
    float blo = __fadd_rn(__fmul_rn(f0, kD), -1.0f);
    float bhi = __fadd_rn(__fmul_rn(__fadd_rn(f0, 1.0f), kD), -1.0f);
    bool  up = (xc >= bhi);
    int   j  = i0 + (up ? 1 : 0);
    float bj = up ? bhi : blo;
    float dx = xc - bj;
    float4 c = sc[cbase + j];
    return __builtin_fmaf(__builtin_fmaf(__builtin_fmaf(c.w, dx, c.z), dx, c.y), dx, c.x);
}

__global__ __launch_bounds__(512, 4)
void kan_kernel(const float4* __restrict__ xq,
                const float* __restrict__ w,
                const float* __restrict__ bias,
                const float* __restrict__ coeffs,
                float* __restrict__ out,
                float4 bp)   // exact f32 bits of bp[6..9] (XLA linspace semantics)
{
    __shared__ float4 sc[NC4];        // 30720 B -> 2 blocks/CU
    __shared__ float4 sw4[IHALF / 4];

    const int o = blockIdx.x >> 1;
    const int h = blockIdx.x & 1;
    const int b = threadIdx.x;

    const float4* gsrc = reinterpret_cast<const float4*>(coeffs)
                         + ((size_t)o * IN_F + h * IHALF) * NINT;
    #pragma unroll
    for (int k = 0; k < 4; ++k) {
        int t = b + k * 512;
        if (t < NC4) {
            __builtin_amdgcn_global_load_lds((gvoid_t*)(gsrc + t), (lvoid_t*)(sc + t), 16, 0, 0);
        }
    }
    if (b < IHALF / 4) {
        sw4[b] = reinterpret_cast<const float4*>(w + (size_t)o * IN_F + h * IHALF)[b];
    }
    __syncthreads();

    const float BP6 = bp.x, BP7 = bp.y, BP8 = bp.z, BP9 = bp.w;
    float a0 = 0.f, a1 = 0.f, a2 = 0.f, a3 = 0.f;

    #pragma unroll 2
    for (int i4 = 0; i4 < IHALF / 4; ++i4) {
        // phase 1: 12 uniform-address candidate loads (prefetchable, broadcast)
        const float4* crow = sc + i4 * 4 * NINT;
        float4 c6[4], c7[4], c8[4];
        #pragma unroll
        for (int e = 0; e < 4; ++e) {
            c6[e] = crow[e * NINT + 6];
            c7[e] = crow[e * NINT + 7];
            c8[e] = crow[e * NINT + 8];
        }

        float4 xv = xq[(h * 32 + i4) * 512 + b];  // coalesced
        float4 wv = sw4[i4];
        float wvs[4] = {wv.x, wv.y, wv.z, wv.w};
        float xvs[4] = {xv.x, xv.y, xv.z, xv.w};
        float ys[4];

        // phase 2: per component, wave-uniform hot/cold branch
        #pragma unroll
        for (int e = 0; e < 4; ++e) {
            float wx = wvs[e] * xvs[e];           // ref's exact f32 product
            // outlier = needs bins outside {6,7,8} (or clamping)
            if (__builtin_expect(__ballot(wx < BP6 || wx >= BP9) != 0ull, 0)) {
                ys[e] = kan_slow(wvs[e], xvs[e], sc, (i4 * 4 + e) * NINT);
            } else {
                bool m7 = wx >= BP7, m8 = wx >= BP8;   // exact searchsorted compares
                float bj = m8 ? BP8 : (m7 ? BP7 : BP6);
                float4 t, cc;
                t.x = m7 ? c7[e].x : c6[e].x;  cc.x = m8 ? c8[e].x : t.x;
                t.y = m7 ? c7[e].y : c6[e].y;  cc.y = m8 ? c8[e].y : t.y;
                t.z = m7 ? c7[e].z : c6[e].z;  cc.z = m8 ? c8[e].z : t.z;
                t.w = m7 ? c7[e].w : c6[e].w;  cc.w = m8 ? c8[e].w : t.w;
                float dx = wx - bj;                    // ref's exact f32 sub
                ys[e] = __builtin_fmaf(__builtin_fmaf(__builtin_fmaf(
                            cc.w, dx, cc.z), dx, cc.y), dx, cc.x);
            }
        }
        a0 += ys[0]; a1 += ys[1]; a2 += ys[2]; a3 += ys[3];
    }

    float acc = (a0 + a1) + (a2 + a3);
    if (h == 0) acc += bias[o];
    // out zeroed by prep_kernel; exactly 2 commutative adds from exact 0.
    atomicAdd(out + (size_t)b * OUT_F + o, acc);
}

extern "C" void kernel_launch(void* const* d_in, const int* in_sizes, int n_in,
                              void* d_out, int out_size, void* d_ws, size_t ws_size,
                              hipStream_t stream) {
    (void)ws_size; (void)out_size;

    const float *x = nullptr, *wgt = nullptr, *bias = nullptr, *coeffs = nullptr;
    for (int i = 0; i < n_in; ++i) {
        switch (in_sizes[i]) {
            case 512 * 256:           x      = (const float*)d_in[i]; break;
            case 256 * 256:           wgt    = (const float*)d_in[i]; break;
            case 256:                 bias   = (const float*)d_in[i]; break;
            case 256 * 256 * 15 * 4:  coeffs = (const float*)d_in[i]; break;
            default: break;
        }
    }

    float4* xq = (float4*)d_ws;  // 512 KB scratch: transposed x

    // exact f32 bits of jnp.linspace breakpoints 6..9 (pure f32 arithmetic,
    // separate mul/add roundings, volatile blocks host FMA contraction)
    volatile float kd = 2.0f / 15.0f;
    float bpv[4];
    for (int k = 0; k < 4; ++k) {
        volatile float p = (float)(k + 6) * kd;
        bpv[k] = p + (-1.0f);
    }
    float4 bp = make_float4(bpv[0], bpv[1], bpv[2], bpv[3]);

    prep_kernel<<<128, 256, 0, stream>>>(x, xq, (float4*)d_out);
    kan_kernel<<<2 * OUT_F, B_SZ, 0, stream>>>(xq, wgt, bias, coeffs, (float*)d_out, bp);
}